// Round 13
// baseline (45.447 us; speedup 1.0000x reference)
//
#include <hip/hip_runtime.h>

// ROIAlign3D: features [B=2,C=128,D=16,H=64,W=64] f32, rois [B,N=64,6] f32
// out [B,N,C,7,7,7] f32. SAMPLING_RATIO=2, ALIGNED=true, SPATIAL_SCALE=1.
//
// Round 13: v12 cell phase; LDS/latency cuts:
//  - float2 staging: 8B/lane loads (coalesced), ds_write_b64, half the
//    staging instructions.
//  - even stride s in {14,18,22,26} (s%4==2 -> gcd(s,32)=2, free 2-way);
//    lo[2] rounded even so global float2 loads are 8B aligned.
//  - cell tables loaded from global ws at kernel start (L2-hot, latency
//    hidden under staging); z-collapse computed pre-barrier. No LDS tbl.
constexpr int Bc = 2, Nc = 64, Cc = 128, Dc = 16, Hc = 64, Wc = 64;
constexpr int OD = 7, OH = 7, OW = 7;
constexpr int CELLS = OD * OH * OW;          // 343
constexpr int DHW = Dc * Hc * Wc, HW = Hc * Wc;
constexpr int MAXZ = 10, MAXY = 25;
constexpr int SUBSZ = MAXZ * MAXY * 26;      // 6500 (rows*s worst case)
constexpr int BLOB = 176;                    // dwords per ROI in ws
constexpr int TZP = 0, WZP = 28, TYP = 56, WYB = 84, WXB = 112, TXO = 140;

typedef _Float16 h2f __attribute__((ext_vector_type(2)));

__device__ inline unsigned pk_f16(float a, float b) {
    return __builtin_bit_cast(unsigned, __builtin_amdgcn_cvt_pkrtz(a, b));
}
__device__ inline h2f uh(unsigned u) { return __builtin_bit_cast(h2f, u); }

__global__ __launch_bounds__(128) void roi_pre(
    const float* __restrict__ rois, unsigned* __restrict__ ws)
{
    int r = threadIdx.x;
    if (r >= Bc * Nc) return;
    const float* rp = rois + r * 6;
    float r1a[3] = {rp[0] - 0.5f, rp[1] - 0.5f, rp[2] - 0.5f};
    float r2a[3] = {rp[3] - 0.5f, rp[4] - 0.5f, rp[5] - 0.5f};
    const int dims[3] = {Dc, Hc, Wc};
    const int maxn[3] = {MAXZ, MAXY, 25};
    float bs[3]; int lo[3], ncnt[3];
    #pragma unroll
    for (int a = 0; a < 3; ++a) {
        bs[a] = fmaxf(r2a[a] - r1a[a], 1e-6f) * (1.0f / 7.0f);
        float smin = r1a[a] + 0.25f * bs[a];
        float smax = r1a[a] + 6.75f * bs[a];
        int l = max(0, (int)floorf(smin));
        int h = min(dims[a] - 1, (int)floorf(smax) + 1);
        lo[a] = l;
        ncnt[a] = min(h - l + 1, maxn[a]);
    }
    // x: round lo down to even (8B-aligned global float2), xn grows <=1.
    {
        int l = lo[2] & ~1;
        ncnt[2] = min(ncnt[2] + (lo[2] - l), 26);
        lo[2] = l;
    }
    int zn = ncnt[0], yn = ncnt[1], xn = ncnt[2];
    int s  = (xn <= 14) ? 14 : (xn <= 18) ? 18 : (xn <= 22) ? 22 : 26;
    int hp = s >> 1;                          // pairs per row
    int rows = zn * yn;
    int zstride = yn * s;
    int gz = lo[0] * HW + lo[1] * Wc + lo[2];
    unsigned m32p = 0xFFFFFFFFu / (unsigned)hp + 1u;
    unsigned m32y = 0xFFFFFFFFu / (unsigned)yn + 1u;

    unsigned* blob = ws + r * BLOB;
    blob[0] = (unsigned)(rows * hp);          // total pair-slots
    blob[1] = (unsigned)hp;  blob[2] = (unsigned)xn;  blob[3] = (unsigned)yn;
    blob[4] = (unsigned)gz;  blob[5] = m32p;  blob[6] = m32y;
    blob[7] = (unsigned)zn;  blob[8] = (unsigned)zstride;
    blob[9] = (unsigned)s;
    unsigned* tb = blob + 12;                 // 16B-aligned tables
    for (int m = 0; m < 14; ++m) {
        #pragma unroll
        for (int a = 0; a < 3; ++a) {
            float v = r1a[a] + ((float)m + 0.5f) * 0.5f * bs[a];
            float f = floorf(v);
            float l = v - f;
            int i0 = (int)f;
            int d  = dims[a];
            float w0 = (i0 >= 0 && i0 < d) ? 1.0f - l : 0.0f;
            float w1 = (i0 + 1 < d) ? l : 0.0f;
            if (a == 0) {
                int c0 = min(max(i0 - lo[0], 0), zn - 1);
                int c1 = min(max(i0 + 1 - lo[0], 0), zn - 1);
                tb[TZP + 2 * m]     = (unsigned)c0;     // RAW z rows
                tb[TZP + 2 * m + 1] = (unsigned)c1;
                ((float*)tb)[WZP + 2 * m]     = w0;
                ((float*)tb)[WZP + 2 * m + 1] = w1;
            } else if (a == 1) {
                int c0 = min(max(i0 - lo[1], 0), yn - 1);
                int c1 = min(max(i0 + 1 - lo[1], 0), yn - 1);
                tb[TYP + 2 * m]     = (unsigned)(c0 * s);
                tb[TYP + 2 * m + 1] = (unsigned)(c1 * s);
                tb[WYB + 2 * m]     = pk_f16(w0, w0);   // broadcast pairs
                tb[WYB + 2 * m + 1] = pk_f16(w1, w1);
            } else {
                int c0 = min(max(i0 - lo[2], -1), xn - 1);  // pair trick
                tb[TXO + m] = (unsigned)c0;
                tb[WXB + 2 * m]     = pk_f16(w0, w0);
                tb[WXB + 2 * m + 1] = pk_f16(w1, w1);
            }
        }
    }
}

__global__ __launch_bounds__(384) void roialign3d_v13(
    const float* __restrict__ feat, const unsigned* __restrict__ ws,
    float* __restrict__ out)
{
    __shared__ __align__(16) unsigned sub[SUBSZ + 2];  // [0..1] front pads

    const int blk = blockIdx.x;
    const int cp  = blk & 63;
    const int n   = (blk >> 6) & 63;
    const int b   = blk >> 12;
    const int tid = threadIdx.x;

    const unsigned* blob = ws + (unsigned)(b * Nc + n) * BLOB;
    const int totalp  = (int)blob[0];
    const int hp      = (int)blob[1];
    const int xn      = (int)blob[2];
    const int yn      = (int)blob[3];
    const int gz      = (int)blob[4];
    const unsigned m32p = blob[5];
    const unsigned m32y = blob[6];
    const int zn      = (int)blob[7];
    const int zstride = (int)blob[8];
    const unsigned* tb = blob + 12;

    // ---- Early: cell-table vector loads from global (L2-hot). ----
    const bool isCell = tid < CELLS;
    int4 tzr; float4 wzv; int4 ty; uint4 wyb, wxb; int2 xop;
    if (isCell) {
        int i   = tid / 49;
        int rem = tid - i * 49;
        int j   = rem / 7;
        int k   = rem - j * 7;
        tzr = *(const int4*)&tb[TZP + 4 * i];
        wzv = *(const float4*)&tb[WZP + 4 * i];
        ty  = *(const int4*)&tb[TYP + 4 * j];
        wyb = *(const uint4*)&tb[WYB + 4 * j];
        wxb = *(const uint4*)&tb[WXB + 4 * k];
        xop = *(const int2*)&tb[TXO + 2 * k];
    }
    if (tid == 352) sub[0] = 0;               // front pads (x corner at -1)
    if (tid == 353) sub[1] = 0;

    // ---- Stage subvolume: float2 per lane (8B coalesced), b64 LDS write. ----
    const int c0ch = cp * 2;
    const float* fb = feat + ((size_t)b * Cc + c0ch) * DHW;
    for (int p = tid; p < totalp; p += 384) {
        int row = (int)__umulhi((unsigned)p, m32p);   // p / hp
        int t   = p - row * hp;
        int x0  = t << 1;
        int z   = (int)__umulhi((unsigned)row, m32y); // row / yn
        int y   = row - z * yn;
        int g   = gz + (z << 12) + (y << 6) + x0;     // HW=4096, Wc=64
        unsigned d0, d1;
        if (x0 + 1 < xn) {
            float2 va = *(const float2*)(fb + g);
            float2 vb = *(const float2*)(fb + g + DHW);
            d0 = pk_f16(va.x, vb.x);
            d1 = pk_f16(va.y, vb.y);
        } else {
            int gc = g - (x0 - (xn - 1));             // clamp to xn-1
            d0 = pk_f16(fb[gc], fb[gc + DHW]);
            d1 = d0;
        }
        *(uint2*)&sub[2 + row * (hp << 1) + x0] = make_uint2(d0, d1);
    }

    // ---- Pre-barrier: z 3-slot collapse (tables only). ----
    int zb0 = 0, zb1 = 0, zb2 = 0; float cz0 = 0, cz1 = 0, cz2 = 0;
    if (isCell) {
        int c0z = tzr.x;
        int p1 = tzr.y - c0z, p2 = tzr.z - c0z, p3 = tzr.w - c0z;
        cz0 = wzv.x + (p1 == 0 ? wzv.y : 0.0f)
            + (p2 == 0 ? wzv.z : 0.0f) + (p3 == 0 ? wzv.w : 0.0f);
        cz1 = (p1 == 1 ? wzv.y : 0.0f)
            + (p2 == 1 ? wzv.z : 0.0f) + (p3 == 1 ? wzv.w : 0.0f);
        cz2 = (p3 == 2 ? wzv.w : 0.0f);
        zb0 = c0z * zstride;
        zb1 = min(c0z + 1, zn - 1) * zstride;
        zb2 = min(c0z + 2, zn - 1) * zstride;
    }
    __syncthreads();

    if (isCell) {
        const unsigned* G = sub + 2;
        h2f wx00 = uh(wxb.x), wx01 = uh(wxb.y);
        h2f wx10 = uh(wxb.z), wx11 = uh(wxb.w);
        const h2f wys[4] = {uh(wyb.x), uh(wyb.y), uh(wyb.z), uh(wyb.w)};
        const int   zbs[3] = {zb0, zb1, zb2};
        const float czs[3] = {cz0, cz1, cz2};
        const int   yo[4]  = {ty.x, ty.y, ty.z, ty.w};
        const int xo0 = xop.x, xo1 = xop.y;

        float a0 = 0.0f, a1 = 0.0f;
        #pragma unroll
        for (int d = 0; d < 3; ++d) {
            int zb = zbs[d];
            h2f sacc = {(_Float16)0, (_Float16)0};
            #pragma unroll
            for (int yi = 0; yi < 4; ++yi) {
                int base = zb + yo[yi];
                h2f A0 = uh(G[base + xo0]), A1 = uh(G[base + xo0 + 1]);
                h2f B0 = uh(G[base + xo1]), B1 = uh(G[base + xo1 + 1]);
                h2f xr = A0 * wx00 + A1 * wx01 + B0 * wx10 + B1 * wx11;
                sacc = sacc + wys[yi] * xr;
            }
            a0 = fmaf(czs[d], (float)sacc.x, a0);
            a1 = fmaf(czs[d], (float)sacc.y, a1);
        }
        size_t obase = ((size_t)(b * Nc + n) * Cc + c0ch) * CELLS;
        out[obase + tid]         = a0 * 0.125f;
        out[obase + CELLS + tid] = a1 * 0.125f;
    }
}

extern "C" void kernel_launch(void* const* d_in, const int* in_sizes, int n_in,
                              void* d_out, int out_size, void* d_ws, size_t ws_size,
                              hipStream_t stream) {
    const float* feat = (const float*)d_in[0];
    const float* rois = (const float*)d_in[1];
    float* out = (float*)d_out;
    unsigned* ws = (unsigned*)d_ws;
    hipLaunchKernelGGL(roi_pre, dim3(1), dim3(128), 0, stream, rois, ws);
    hipLaunchKernelGGL(roialign3d_v13, dim3(Bc * Nc * (Cc / 2)), dim3(384), 0,
                       stream, feat, (const unsigned*)ws, out);
}

// Round 14
// 43.138 us; speedup vs baseline: 1.0535x; 1.0535x over previous
//
#include <hip/hip_runtime.h>

// ROIAlign3D: features [B=2,C=128,D=16,H=64,W=64] f32, rois [B,N=64,6] f32
// out [B,N,C,7,7,7] f32. SAMPLING_RATIO=2, ALIGNED=true, SPATIAL_SCALE=1.
//
// Round 14: v12 main kernel EXACTLY (best measured main: ~38.5us; packed-f16
// cell math, LDS table copy, magic-div staging). v13's float2-staging +
// global-table reads regressed the main kernel -> reverted.
// roi_pre parallelized: 128 blocks x 64 threads (1 block/ROI, 1 table
// entry/thread) -> pre cost drops from ~5.6us (serial 1-block) to ~2us.
constexpr int Bc = 2, Nc = 64, Cc = 128, Dc = 16, Hc = 64, Wc = 64;
constexpr int OD = 7, OH = 7, OW = 7;
constexpr int CELLS = OD * OH * OW;          // 343
constexpr int DHW = Dc * Hc * Wc, HW = Hc * Wc;
constexpr int MAXZ = 10, MAXY = 25, MAXX = 25;
constexpr int SUBSZ = MAXZ * MAXY * (MAXX + 1);   // 6500
constexpr int BLOB = 176;                    // dwords per ROI in ws
// table layout (dword offsets inside tbl / blob+10)
constexpr int TZP = 0, WZP = 28, TYP = 56, WYB = 84, WXB = 112, TXO = 140;
constexpr int TBLN = 154;

typedef _Float16 h2f __attribute__((ext_vector_type(2)));

__device__ inline unsigned pk_f16(float a, float b) {
    return __builtin_bit_cast(unsigned, __builtin_amdgcn_cvt_pkrtz(a, b));
}
__device__ inline h2f uh(unsigned u) { return __builtin_bit_cast(h2f, u); }

__global__ __launch_bounds__(64) void roi_pre(
    const float* __restrict__ rois, unsigned* __restrict__ ws)
{
    const int r = blockIdx.x;                 // one block per ROI
    const int t = threadIdx.x;
    const float* rp = rois + r * 6;
    float r1a[3] = {rp[0] - 0.5f, rp[1] - 0.5f, rp[2] - 0.5f};
    float r2a[3] = {rp[3] - 0.5f, rp[4] - 0.5f, rp[5] - 0.5f};
    const int dims[3] = {Dc, Hc, Wc};
    const int maxn[3] = {MAXZ, MAXY, MAXX};
    float bs[3]; int lo[3], ncnt[3];
    #pragma unroll
    for (int a = 0; a < 3; ++a) {
        bs[a] = fmaxf(r2a[a] - r1a[a], 1e-6f) * (1.0f / 7.0f);
        float smin = r1a[a] + 0.25f * bs[a];
        float smax = r1a[a] + 6.75f * bs[a];
        int l = max(0, (int)floorf(smin));
        int h = min(dims[a] - 1, (int)floorf(smax) + 1);
        lo[a] = l;
        ncnt[a] = min(h - l + 1, maxn[a]);
    }
    int zn = ncnt[0], yn = ncnt[1], xn = ncnt[2];
    int xnp = xn | 1;                         // odd stride
    int rows = zn * yn;
    unsigned* blob = ws + r * BLOB;

    if (t == 63) {
        blob[0] = (unsigned)(rows * xnp);
        blob[1] = (unsigned)xnp;
        blob[2] = (unsigned)xn;
        blob[3] = (unsigned)yn;
        blob[4] = (unsigned)(lo[0] * HW + lo[1] * Wc + lo[2]);
        blob[5] = 0xFFFFFFFFu / (unsigned)xnp + 1u;
        blob[6] = 0xFFFFFFFFu / (unsigned)yn + 1u;
        blob[7] = (unsigned)zn;
        blob[8] = (unsigned)(yn * xnp);
        blob[9] = 0;
    }
    if (t < 42) {
        int a = t / 14, m = t - a * 14;
        unsigned* tb = blob + 10;
        float v = r1a[a] + ((float)m + 0.5f) * 0.5f * bs[a];
        float f = floorf(v);
        float l = v - f;
        int i0 = (int)f;
        int d  = dims[a];
        float w0 = (i0 >= 0 && i0 < d) ? 1.0f - l : 0.0f;
        float w1 = (i0 + 1 < d) ? l : 0.0f;
        if (a == 0) {
            int c0 = min(max(i0 - lo[0], 0), zn - 1);
            int c1 = min(max(i0 + 1 - lo[0], 0), zn - 1);
            tb[TZP + 2 * m]     = (unsigned)c0;     // RAW z rows
            tb[TZP + 2 * m + 1] = (unsigned)c1;
            ((float*)tb)[WZP + 2 * m]     = w0;
            ((float*)tb)[WZP + 2 * m + 1] = w1;
        } else if (a == 1) {
            int c0 = min(max(i0 - lo[1], 0), yn - 1);
            int c1 = min(max(i0 + 1 - lo[1], 0), yn - 1);
            tb[TYP + 2 * m]     = (unsigned)(c0 * xnp);
            tb[TYP + 2 * m + 1] = (unsigned)(c1 * xnp);
            tb[WYB + 2 * m]     = pk_f16(w0, w0);   // broadcast pairs
            tb[WYB + 2 * m + 1] = pk_f16(w1, w1);
        } else {
            int c0 = min(max(i0 - lo[2], -1), xn - 1);  // pair trick
            tb[TXO + m] = (unsigned)c0;
            tb[WXB + 2 * m]     = pk_f16(w0, w0);
            tb[WXB + 2 * m + 1] = pk_f16(w1, w1);
        }
    }
}

__global__ __launch_bounds__(384) void roialign3d_v14(
    const float* __restrict__ feat, const unsigned* __restrict__ ws,
    float* __restrict__ out)
{
    __shared__ __align__(16) unsigned sub[SUBSZ + 2];
    __shared__ __align__(16) unsigned tbl[TBLN];

    const int blk = blockIdx.x;
    const int cp  = blk & 63;
    const int n   = (blk >> 6) & 63;
    const int b   = blk >> 12;
    const int tid = threadIdx.x;

    const unsigned* blob = ws + (unsigned)(b * Nc + n) * BLOB;
    const int total   = (int)blob[0];
    const int xnp     = (int)blob[1];
    const int xn      = (int)blob[2];
    const int yn      = (int)blob[3];
    const int gz      = (int)blob[4];
    const unsigned m32x = blob[5];
    const unsigned m32y = blob[6];
    const int zn      = (int)blob[7];
    const int zstride = (int)blob[8];

    if (tid < TBLN) tbl[tid] = blob[10 + tid];
    if (tid == 352) sub[0] = 0;               // front pad (x corner at -1)
    if (tid == 353) sub[1 + total] = 0;       // end pad

    // ---- Stage subvolume (fp16x2), lane-consecutive, magic-div. ----
    const int c0ch = cp * 2;
    const float* fb = feat + ((size_t)b * Cc + c0ch) * DHW;
    for (int p = tid; p < total; p += 384) {
        int row = (int)__umulhi((unsigned)p, m32x);   // p / xnp
        int x   = p - row * xnp;
        int xs  = min(x, xn - 1);
        int z   = (int)__umulhi((unsigned)row, m32y); // row / yn
        int y   = row - z * yn;
        int g   = gz + (z << 12) + (y << 6) + xs;     // HW=4096, Wc=64
        sub[1 + p] = pk_f16(fb[g], fb[g + DHW]);
    }
    __syncthreads();

    if (tid < CELLS) {
        int i   = tid / 49;
        int rem = tid - i * 49;
        int j   = rem / 7;
        int k   = rem - j * 7;
        int4   tzr = *(const int4*)&tbl[TZP + 4 * i];   // raw z rows
        float4 wzv = *(const float4*)&tbl[WZP + 4 * i];
        int4   ty  = *(const int4*)&tbl[TYP + 4 * j];   // premult xnp
        uint4  wyb = *(const uint4*)&tbl[WYB + 4 * j];
        uint4  wxb = *(const uint4*)&tbl[WXB + 4 * k];
        int xo0 = (int)tbl[TXO + 2 * k], xo1 = (int)tbl[TXO + 2 * k + 1];

        const unsigned* G = sub + 1;
        h2f wx00 = uh(wxb.x), wx01 = uh(wxb.y);
        h2f wx10 = uh(wxb.z), wx11 = uh(wxb.w);
        const h2f wys[4] = {uh(wyb.x), uh(wyb.y), uh(wyb.z), uh(wyb.w)};

        // z 3-slot collapse: corners lie in {c0, c0+1, c0+2}.
        int c0z = tzr.x;
        int p1 = tzr.y - c0z, p2 = tzr.z - c0z, p3 = tzr.w - c0z;
        float cz0 = wzv.x + (p1 == 0 ? wzv.y : 0.0f)
                  + (p2 == 0 ? wzv.z : 0.0f) + (p3 == 0 ? wzv.w : 0.0f);
        float cz1 = (p1 == 1 ? wzv.y : 0.0f)
                  + (p2 == 1 ? wzv.z : 0.0f) + (p3 == 1 ? wzv.w : 0.0f);
        float cz2 = (p3 == 2 ? wzv.w : 0.0f);
        int zb0 = c0z * zstride;
        int zb1 = min(c0z + 1, zn - 1) * zstride;
        int zb2 = min(c0z + 2, zn - 1) * zstride;

        const int   zbs[3] = {zb0, zb1, zb2};
        const float czs[3] = {cz0, cz1, cz2};
        const int   yo[4]  = {ty.x, ty.y, ty.z, ty.w};

        float a0 = 0.0f, a1 = 0.0f;
        #pragma unroll
        for (int d = 0; d < 3; ++d) {
            int zb = zbs[d];
            h2f s = {(_Float16)0, (_Float16)0};
            #pragma unroll
            for (int yi = 0; yi < 4; ++yi) {
                int base = zb + yo[yi];
                h2f A0 = uh(G[base + xo0]), A1 = uh(G[base + xo0 + 1]);
                h2f B0 = uh(G[base + xo1]), B1 = uh(G[base + xo1 + 1]);
                h2f xr = A0 * wx00 + A1 * wx01 + B0 * wx10 + B1 * wx11;
                s = s + wys[yi] * xr;
            }
            a0 = fmaf(czs[d], (float)s.x, a0);
            a1 = fmaf(czs[d], (float)s.y, a1);
        }
        size_t obase = ((size_t)(b * Nc + n) * Cc + c0ch) * CELLS;
        out[obase + tid]         = a0 * 0.125f;
        out[obase + CELLS + tid] = a1 * 0.125f;
    }
}

extern "C" void kernel_launch(void* const* d_in, const int* in_sizes, int n_in,
                              void* d_out, int out_size, void* d_ws, size_t ws_size,
                              hipStream_t stream) {
    const float* feat = (const float*)d_in[0];
    const float* rois = (const float*)d_in[1];
    float* out = (float*)d_out;
    unsigned* ws = (unsigned*)d_ws;
    hipLaunchKernelGGL(roi_pre, dim3(Bc * Nc), dim3(64), 0, stream, rois, ws);
    hipLaunchKernelGGL(roialign3d_v14, dim3(Bc * Nc * (Cc / 2)), dim3(384), 0,
                       stream, feat, (const unsigned*)ws, out);
}

// Round 15
// 39.208 us; speedup vs baseline: 1.1591x; 1.1002x over previous
//
#include <hip/hip_runtime.h>

// ROIAlign3D: features [B=2,C=128,D=16,H=64,W=64] f32, rois [B,N=64,6] f32
// out [B,N,C,7,7,7] f32. SAMPLING_RATIO=2, ALIGNED=true, SPATIAL_SCALE=1.
//
// Round 15 = ledger intersection:
//  - v11 single-kernel, single-barrier skeleton (42-thread in-block table
//    build concurrent with staging; no pre-kernel launch, no ws round-trip).
//  - v12 packed-f16 broadcast weight tables + packed cell math (VALU cut).
//  - v11 magic-div lane-consecutive staging, tight odd stride.
//  - v9 z 3-slot collapse (12 gather points/cell).
constexpr int Bc = 2, Nc = 64, Cc = 128, Dc = 16, Hc = 64, Wc = 64;
constexpr int OD = 7, OH = 7, OW = 7;
constexpr int CELLS = OD * OH * OW;          // 343
constexpr int DHW = Dc * Hc * Wc, HW = Hc * Wc;
constexpr int MAXZ = 10, MAXY = 25, MAXX = 25;
constexpr int SUBSZ = MAXZ * MAXY * (MAXX + 1);   // 6500

typedef _Float16 h2f __attribute__((ext_vector_type(2)));

__device__ inline unsigned pk_f16(float a, float b) {
    return __builtin_bit_cast(unsigned, __builtin_amdgcn_cvt_pkrtz(a, b));
}
__device__ inline h2f uh(unsigned u) { return __builtin_bit_cast(h2f, u); }

__global__ __launch_bounds__(384) void roialign3d_v15(
    const float* __restrict__ feat, const float* __restrict__ rois,
    float* __restrict__ out)
{
    __shared__ __align__(16) unsigned sub[SUBSZ + 2];
    __shared__ __align__(16) int2     tzp[14];   // raw z rows (c0,c1)
    __shared__ __align__(16) float2   wzp[14];
    __shared__ __align__(16) int2     typ[14];   // premult xnp
    __shared__ __align__(16) unsigned wyb[28];   // broadcast f16 pairs
    __shared__ __align__(16) unsigned wxb[28];
    __shared__ __align__(16) int      txo[14];

    const int blk = blockIdx.x;
    const int cp  = blk & 63;
    const int n   = (blk >> 6) & 63;
    const int b   = blk >> 12;
    const int tid = threadIdx.x;

    const float* rp = rois + (size_t)(b * Nc + n) * 6;
    float r1a[3] = {rp[0] - 0.5f, rp[1] - 0.5f, rp[2] - 0.5f};
    float r2a[3] = {rp[3] - 0.5f, rp[4] - 0.5f, rp[5] - 0.5f};
    const int dims[3] = {Dc, Hc, Wc};
    const int maxn[3] = {MAXZ, MAXY, MAXX};

    float bs[3]; int lo[3], ncnt[3];
    #pragma unroll
    for (int a = 0; a < 3; ++a) {
        bs[a] = fmaxf(r2a[a] - r1a[a], 1e-6f) * (1.0f / 7.0f);
        float smin = r1a[a] + 0.25f * bs[a];
        float smax = r1a[a] + 6.75f * bs[a];
        int l = max(0, (int)floorf(smin));
        int h = min(dims[a] - 1, (int)floorf(smax) + 1);
        lo[a] = l;
        ncnt[a] = min(h - l + 1, maxn[a]);    // maxn clamp = memory safety only
    }
    const int zn = ncnt[0], yn = ncnt[1], xn = ncnt[2];
    const int xnp = xn | 1;                   // odd stride (coprime w/ 32)
    const int rows = zn * yn;
    const int zstride = yn * xnp;

    // Axis tables (42 threads), packed-f16 broadcast weights for y/x.
    if (tid < 42) {
        int a = tid / 14, m = tid - a * 14;
        float v = r1a[a] + ((float)m + 0.5f) * 0.5f * bs[a];
        float f = floorf(v);
        float l = v - f;
        int i0 = (int)f;
        int d  = dims[a];
        float w0 = (i0 >= 0 && i0 < d) ? 1.0f - l : 0.0f;
        float w1 = (i0 + 1 < d) ? l : 0.0f;
        if (a == 0) {
            int c0 = min(max(i0 - lo[0], 0), zn - 1);
            int c1 = min(max(i0 + 1 - lo[0], 0), zn - 1);
            tzp[m] = make_int2(c0, c1);              // RAW rows
            wzp[m] = make_float2(w0, w1);
        } else if (a == 1) {
            int c0 = min(max(i0 - lo[1], 0), yn - 1);
            int c1 = min(max(i0 + 1 - lo[1], 0), yn - 1);
            typ[m] = make_int2(c0 * xnp, c1 * xnp);
            wyb[2 * m]     = pk_f16(w0, w0);
            wyb[2 * m + 1] = pk_f16(w1, w1);
        } else {
            // pair trick: corners are (c0, c0+1); c0 in [-1, xn-1].
            int c0 = min(max(i0 - lo[2], -1), xn - 1);
            txo[m] = c0;
            wxb[2 * m]     = pk_f16(w0, w0);
            wxb[2 * m + 1] = pk_f16(w1, w1);
        }
    }
    if (tid == 64) sub[0] = 0;                        // front pad (c0 = -1)
    if (tid == 65) sub[1 + rows * xnp] = 0;           // end pad

    // ---- Stage subvolume (fp16x2), lane-consecutive, magic-div. ----
    const int c0ch = cp * 2;
    const float* fb = feat + ((size_t)b * Cc + c0ch) * DHW;
    const unsigned m32x = 0xFFFFFFFFu / (unsigned)xnp + 1u;
    const unsigned m32y = 0xFFFFFFFFu / (unsigned)yn + 1u;
    const int gz = lo[0] * HW + lo[1] * Wc + lo[2];
    const int total = rows * xnp;
    for (int p = tid; p < total; p += 384) {
        int row = (int)__umulhi((unsigned)p, m32x);   // p / xnp
        int x   = p - row * xnp;
        int xs  = min(x, xn - 1);
        int z   = (int)__umulhi((unsigned)row, m32y); // row / yn
        int y   = row - z * yn;
        int g   = gz + (z << 12) + (y << 6) + xs;     // HW=4096, Wc=64
        sub[1 + p] = pk_f16(fb[g], fb[g + DHW]);
    }
    __syncthreads();

    if (tid < CELLS) {
        int i   = tid / 49;
        int rem = tid - i * 49;
        int j   = rem / 7;
        int k   = rem - j * 7;
        int4   tzr  = *(const int4*)&tzp[2 * i];    // (c0,c1,c0',c1') raw
        float4 wzv  = *(const float4*)&wzp[2 * i];
        int4   ty   = *(const int4*)&typ[2 * j];
        uint4  wyb4 = *(const uint4*)&wyb[4 * j];
        uint4  wxb4 = *(const uint4*)&wxb[4 * k];
        int xo0 = txo[2 * k], xo1 = txo[2 * k + 1];

        const unsigned* G = sub + 1;
        h2f wx00 = uh(wxb4.x), wx01 = uh(wxb4.y);
        h2f wx10 = uh(wxb4.z), wx11 = uh(wxb4.w);
        const h2f wys[4] = {uh(wyb4.x), uh(wyb4.y), uh(wyb4.z), uh(wyb4.w)};

        // z 3-slot collapse: corners lie in {c0, c0+1, c0+2}.
        int c0z = tzr.x;
        int p1 = tzr.y - c0z, p2 = tzr.z - c0z, p3 = tzr.w - c0z;
        float cz0 = wzv.x + (p1 == 0 ? wzv.y : 0.0f)
                  + (p2 == 0 ? wzv.z : 0.0f) + (p3 == 0 ? wzv.w : 0.0f);
        float cz1 = (p1 == 1 ? wzv.y : 0.0f)
                  + (p2 == 1 ? wzv.z : 0.0f) + (p3 == 1 ? wzv.w : 0.0f);
        float cz2 = (p3 == 2 ? wzv.w : 0.0f);
        int zb0 = c0z * zstride;
        int zb1 = min(c0z + 1, zn - 1) * zstride;
        int zb2 = min(c0z + 2, zn - 1) * zstride;

        const int   zbs[3] = {zb0, zb1, zb2};
        const float czs[3] = {cz0, cz1, cz2};
        const int   yo[4]  = {ty.x, ty.y, ty.z, ty.w};

        float a0 = 0.0f, a1 = 0.0f;
        #pragma unroll
        for (int d = 0; d < 3; ++d) {
            int zb = zbs[d];
            h2f s = {(_Float16)0, (_Float16)0};
            #pragma unroll
            for (int yi = 0; yi < 4; ++yi) {
                int base = zb + yo[yi];
                h2f A0 = uh(G[base + xo0]), A1 = uh(G[base + xo0 + 1]);
                h2f B0 = uh(G[base + xo1]), B1 = uh(G[base + xo1 + 1]);
                h2f xr = A0 * wx00 + A1 * wx01 + B0 * wx10 + B1 * wx11;
                s = s + wys[yi] * xr;
            }
            a0 = fmaf(czs[d], (float)s.x, a0);
            a1 = fmaf(czs[d], (float)s.y, a1);
        }
        size_t obase = ((size_t)(b * Nc + n) * Cc + c0ch) * CELLS;
        out[obase + tid]         = a0 * 0.125f;
        out[obase + CELLS + tid] = a1 * 0.125f;
    }
}

extern "C" void kernel_launch(void* const* d_in, const int* in_sizes, int n_in,
                              void* d_out, int out_size, void* d_ws, size_t ws_size,
                              hipStream_t stream) {
    const float* feat = (const float*)d_in[0];
    const float* rois = (const float*)d_in[1];
    float* out = (float*)d_out;
    hipLaunchKernelGGL(roialign3d_v15, dim3(Bc * Nc * (Cc / 2)), dim3(384), 0,
                       stream, feat, rois, out);
}